// Round 16
// baseline (527.493 us; speedup 1.0000x reference)
//
#include <hip/hip_runtime.h>
#include <hip/hip_bf16.h>

typedef __bf16 bf16x8 __attribute__((ext_vector_type(8)));
typedef float f32x4 __attribute__((ext_vector_type(4)));
typedef __hip_bfloat16 bf16;

static constexpr int NN = 8192;
static constexpr int DD = 128;
static constexpr int KTOP = 1638;   // int(0.2 * 8192)
static constexpr int KSLICE = 4;    // split-K factor for the AV GEMM
static constexpr int KCH = NN / KSLICE;

// ---------------- input dtype detection ----------------
__global__ void detect_dtype(const unsigned short* __restrict__ xin, int* __restrict__ flag) {
  __shared__ int cnt;
  if (threadIdx.x == 0) cnt = 0;
  __syncthreads();
  int c = 0;
  for (int i = threadIdx.x; i < 4096; i += 256) {
    int e = (xin[i] >> 7) & 0xFF;
    if (e >= 0x8A) ++c;
  }
  atomicAdd(&cnt, c);
  __syncthreads();
  if (threadIdx.x == 0) *flag = (cnt > 16) ? 1 : 0;
}

// ---------------- prep: cvt imp + transpose W (dual dtype), 5 blocks ----------------
__global__ void prep(const void* __restrict__ imp_in,
                     const void* __restrict__ W1, const void* __restrict__ W2,
                     float* __restrict__ impf,
                     bf16* __restrict__ Wt1, bf16* __restrict__ Wt2,
                     const int* __restrict__ flag) {
  int isf32 = *flag;
  int b = blockIdx.x;
  if (b == 0) {
    for (int i = threadIdx.x; i < NN; i += 256)
      impf[i] = isf32 ? ((const float*)imp_in)[i] : __bfloat162float(((const bf16*)imp_in)[i]);
  } else {
    int w = b - 1;                    // 0,1 -> W1 l=0,1 ; 2,3 -> W2 l=0,1
    const void* srcv = (w < 2 ? W1 : W2);
    bf16* dst = (w < 2 ? Wt1 : Wt2) + (w & 1) * DD * DD;
    int off = (w & 1) * DD * DD;
    for (int f = threadIdx.x; f < DD * DD; f += 256) {
      int n = f >> 7, k = f & 127;
      float v = isf32 ? ((const float*)srcv)[off + k * DD + n]
                      : __bfloat162float(((const bf16*)srcv)[off + k * DD + n]);
      dst[n * DD + k] = __float2bfloat16(v);
    }
  }
}

// per-row L2 normalize -> xnb (bf16) + plain bf16 cast -> xb.
__global__ void rownorm(const void* __restrict__ src, const int* __restrict__ flag, int raw,
                        bf16* __restrict__ xnb, bf16* __restrict__ xb) {
  int wave = threadIdx.x >> 6;
  int lane = threadIdx.x & 63;
  int row = blockIdx.x * 4 + wave;
  float vx, vy;
  if (raw && *flag == 0) {            // raw bf16 input: unpack a pair
    unsigned u = ((const unsigned*)src)[(long)row * 64 + lane];
    vx = __uint_as_float(u << 16);
    vy = __uint_as_float(u & 0xFFFF0000u);
  } else {
    float2 v = ((const float2*)src)[(long)row * 64 + lane];
    vx = v.x; vy = v.y;
  }
  float s = vx * vx + vy * vy;
  for (int off = 1; off < 64; off <<= 1) s += __shfl_xor(s, off);
  float inv = 1.0f / (sqrtf(s) + 1e-8f);
  int c = lane * 2;
  xb[(long)row * DD + c]      = __float2bfloat16(vx);
  xb[(long)row * DD + c + 1]  = __float2bfloat16(vy);
  xnb[(long)row * DD + c]     = __float2bfloat16(vx * inv);
  xnb[(long)row * DD + c + 1] = __float2bfloat16(vy * inv);
}

// ---------------- rank-5 factorized Gaussian prior ----------------
__launch_bounds__(256)
__global__ void prior_reduce(const float* __restrict__ impf, const bf16* __restrict__ Yt1,
                             float* __restrict__ Mt, float* __restrict__ Gt) {
  __shared__ float red[5][4];
  int c = blockIdx.x;
  int tid = threadIdx.x;
  float s[5] = {0.f, 0.f, 0.f, 0.f, 0.f};
  bool hasY = (c < 128);
  const bf16* col = Yt1 + (long)(hasY ? c : 0) * NN;
  for (int j = tid; j < NN; j += 256) {
    float d = impf[j];
    float a = __expf(d * d * (-1.0f / 32.0f));
    float p = hasY ? a * __bfloat162float(col[j]) : a;
    #pragma unroll
    for (int t = 0; t < 5; ++t) { s[t] += p; p *= d; }
  }
  #pragma unroll
  for (int t = 0; t < 5; ++t)
    for (int off = 1; off < 64; off <<= 1) s[t] += __shfl_xor(s[t], off);
  int wave = tid >> 6, lane = tid & 63;
  if (lane == 0)
    #pragma unroll
    for (int t = 0; t < 5; ++t) red[t][wave] = s[t];
  __syncthreads();
  if (tid == 0) {
    #pragma unroll
    for (int t = 0; t < 5; ++t) {
      float v = red[t][0] + red[t][1] + red[t][2] + red[t][3];
      if (hasY) Mt[t * 128 + c] = v; else Gt[t] = v;
    }
  }
}

// ---------------- K=128 GEMM core (MFMA) with coalesced epilogue ----------------
__device__ __forceinline__ void gemm_core(const bf16* __restrict__ A, const bf16* __restrict__ Bt,
                                          long rowA0, long rowB0, int tid,
                                          bf16* __restrict__ Yt,
                                          bf16* __restrict__ RM, long rm_ld) {
  __shared__ bf16 lA[128][136];
  __shared__ bf16 lB[64][136];
  for (int i = 0; i < 8; ++i) {
    int f = tid + i * 256;
    int r = f >> 4, kg = f & 15;
    *reinterpret_cast<uint4*>(&lA[r][kg * 8]) =
        *reinterpret_cast<const uint4*>(A + (rowA0 + r) * DD + kg * 8);
  }
  for (int i = 0; i < 4; ++i) {
    int f = tid + i * 256;
    int r = f >> 4, kg = f & 15;
    *reinterpret_cast<uint4*>(&lB[r][kg * 8]) =
        *reinterpret_cast<const uint4*>(Bt + (rowB0 + r) * DD + kg * 8);
  }
  __syncthreads();
  int wave = tid >> 6, lane = tid & 63;
  int wm = (wave >> 1) * 64;
  int wn = (wave & 1) * 32;
  int quad = lane >> 4, l16 = lane & 15;
  f32x4 acc[4][2];
  #pragma unroll
  for (int mi = 0; mi < 4; ++mi)
    #pragma unroll
    for (int ni = 0; ni < 2; ++ni) acc[mi][ni] = {0.f, 0.f, 0.f, 0.f};
  #pragma unroll
  for (int ks = 0; ks < 4; ++ks) {
    int kb = ks * 32 + quad * 8;
    bf16x8 af[4], bfr[2];
    #pragma unroll
    for (int mi = 0; mi < 4; ++mi)
      af[mi] = *reinterpret_cast<const bf16x8*>(&lA[wm + mi * 16 + l16][kb]);
    #pragma unroll
    for (int ni = 0; ni < 2; ++ni)
      bfr[ni] = *reinterpret_cast<const bf16x8*>(&lB[wn + ni * 16 + l16][kb]);
    #pragma unroll
    for (int mi = 0; mi < 4; ++mi)
      #pragma unroll
      for (int ni = 0; ni < 2; ++ni)
        acc[mi][ni] = __builtin_amdgcn_mfma_f32_16x16x32_bf16(af[mi], bfr[ni], acc[mi][ni], 0, 0, 0);
  }
  if (Yt) {
    #pragma unroll
    for (int mi = 0; mi < 4; ++mi)
      #pragma unroll
      for (int ni = 0; ni < 2; ++ni) {
        long rowb = rowA0 + wm + mi * 16 + quad * 4;
        long col = rowB0 + wn + ni * 16 + l16;
        bf16 t4[4];
        #pragma unroll
        for (int r = 0; r < 4; ++r) t4[r] = __float2bfloat16(acc[mi][ni][r]);
        *reinterpret_cast<ushort4*>(Yt + col * (long)NN + rowb) =
            *reinterpret_cast<const ushort4*>(t4);
      }
  }
  __syncthreads();
  bf16 (*cs)[72] = reinterpret_cast<bf16(*)[72]>(&lA[0][0]);
  #pragma unroll
  for (int mi = 0; mi < 4; ++mi)
    #pragma unroll
    for (int ni = 0; ni < 2; ++ni)
      #pragma unroll
      for (int r = 0; r < 4; ++r)
        cs[wm + mi * 16 + quad * 4 + r][wn + ni * 16 + l16] = __float2bfloat16(acc[mi][ni][r]);
  __syncthreads();
  #pragma unroll
  for (int i = 0; i < 4; ++i) {
    int f = tid + i * 256;
    int r = f >> 3, sg = f & 7;
    *reinterpret_cast<uint4*>(RM + (rowA0 + r) * rm_ld + rowB0 + sg * 8) =
        *reinterpret_cast<const uint4*>(&cs[r][sg * 8]);
  }
}

// S = Xn @ Xn^T (row-major bf16, ld = NN)
__launch_bounds__(256)
__global__ void gemm_s(const bf16* __restrict__ Xn, bf16* __restrict__ S) {
  gemm_core(Xn, Xn, (long)blockIdx.y * 128, (long)blockIdx.x * 64, threadIdx.x,
            nullptr, S, NN);
}

__launch_bounds__(256)
__global__ void gemm_y_dual(const bf16* __restrict__ xb,
                            const bf16* __restrict__ Wt1, const bf16* __restrict__ Wt2,
                            bf16* __restrict__ Yt1, bf16* __restrict__ Yt2,
                            bf16* __restrict__ Yr1, bf16* __restrict__ Yr2) {
  int sel = blockIdx.x >> 1;
  int bx = blockIdx.x & 1;
  gemm_core(xb, sel ? Wt2 : Wt1, (long)blockIdx.y * 128, (long)bx * 64, threadIdx.x,
            sel ? Yt2 : Yt1, sel ? Yr2 : Yr1, DD);
}

// ---------------- per-row exact top-k threshold + rowsum (R15 structure) ----------------
__device__ __forceinline__ void cnt_half(unsigned t, unsigned bound32, int& c) {
  unsigned long long m; int n;
  asm("v_cmp_lt_u32 %[m], %[t], %[b]\n\t"
      "s_bcnt1_i32_b64 %[n], %[m]\n\t"
      "s_add_i32 %[c], %[c], %[n]"
      : [c]"+s"(c), [m]"=&s"(m), [n]"=&s"(n)
      : [t]"v"(t), [b]"s"(bound32));
}

__launch_bounds__(256)
__global__ void topk_thresh(const bf16* __restrict__ S, unsigned short* __restrict__ kthr,
                            float* __restrict__ invRsF) {
  int wave = threadIdx.x >> 6, lane = threadIdx.x & 63;
  long row = (long)blockIdx.x * 4 + wave;
  const unsigned* rp = reinterpret_cast<const unsigned*>(S + row * NN);
  unsigned kp[64];
  #pragma unroll
  for (int t = 0; t < 16; ++t) {
    uint4 v = *reinterpret_cast<const uint4*>(rp + lane * 4 + t * 256);
    kp[t * 4 + 0] = v.x; kp[t * 4 + 1] = v.y; kp[t * 4 + 2] = v.z; kp[t * 4 + 3] = v.w;
  }
  unsigned cur = 0x3C00u;             // 2^-7
  #pragma unroll
  for (int bit = 9; bit >= 0; --bit) {
    unsigned cand = cur | (1u << bit);
    unsigned pat32 = cand << 16;
    unsigned bound32 = (0x8000u - cand) << 16;
    int c = 0;
    #pragma unroll
    for (int i = 0; i < 64; ++i) {
      cnt_half(kp[i] - pat32, bound32, c);            // high half
      cnt_half((kp[i] << 16) - pat32, bound32, c);    // low half
    }
    if (c >= KTOP) cur = cand;
  }
  unsigned pat32 = cur << 16;
  unsigned bound32 = (0x8000u - cur) << 16;
  float sum = 0.f;
  #pragma unroll
  for (int i = 0; i < 64; ++i) {
    if (kp[i] - pat32 < bound32) sum += __uint_as_float(kp[i] & 0xFFFF0000u);
    unsigned t2 = kp[i] << 16;
    if (t2 - pat32 < bound32) sum += __uint_as_float(t2);
  }
  for (int off = 1; off < 64; off <<= 1) sum += __shfl_xor(sum, off);
  if (lane == 0) {
    invRsF[row] = 1.0f / (sum + 1.0f);
    kthr[row] = (unsigned short)cur;  // raw positive bf16 pattern
  }
}

// ---------------- split-K masked AV GEMM with S RECOMPUTE ----------------
// Instead of reading the 134 MB materialized S, each chunk recomputes its
// S-tile from xnb via MFMA. The accumulation chain (ks=0..3 over K=128, init
// 0) is identical to gemm_s's, so f32 -> __float2bfloat16 -> pattern mask is
// bit-identical to masking the materialized S (exactness preserved).
__launch_bounds__(256)
__global__ void fused_av_recompute(const bf16* __restrict__ Xn, const bf16* __restrict__ Yt2,
                                   const unsigned short* __restrict__ kthr,
                                   float* __restrict__ Pacc) {
  __shared__ bf16 lXr[32][136];   // resident xnb rows [row0, row0+32)
  __shared__ bf16 lXc[64][136];   // streamed xnb rows [kbase+k0, +64) (S columns)
  __shared__ bf16 lY2[128][72];   // streamed Yt2 slice
  __shared__ bf16 lAf[32][72];    // masked S staging
  int tid = threadIdx.x;
  long row0 = (long)blockIdx.x * 32;
  long kbase = (long)blockIdx.y * KCH;
  int wave = tid >> 6, lane = tid & 63;
  int sm = (wave >> 1) * 16;      // S/AV rows for this wave
  int sn = (wave & 1) * 32;       // S cols (within chunk) for this wave
  int wn = (wave & 1) * 64;       // AV output cols for this wave
  int quad = lane >> 4, l16 = lane & 15;
  #pragma unroll
  for (int i = 0; i < 2; ++i) {   // resident A rows: 32 x 16 uint4
    int f = tid + i * 256;
    int r = f >> 4, kg = f & 15;
    *reinterpret_cast<uint4*>(&lXr[r][kg * 8]) =
        *reinterpret_cast<const uint4*>(Xn + (row0 + r) * DD + kg * 8);
  }
  unsigned short p4[4], b4[4];    // per-lane row thresholds (rows sm+quad*4+r)
  #pragma unroll
  for (int r = 0; r < 4; ++r) {
    p4[r] = kthr[row0 + sm + quad * 4 + r];
    b4[r] = (unsigned short)(0x8000u - p4[r]);
  }
  f32x4 accF[4];
  #pragma unroll
  for (int ni = 0; ni < 4; ++ni) accF[ni] = {0.f, 0.f, 0.f, 0.f};
  for (int k0 = 0; k0 < KCH; k0 += 64) {
    __syncthreads();              // protect lXc/lY2/lAf from previous chunk readers
    #pragma unroll
    for (int i = 0; i < 4; ++i) { // lXc: 64 rows x 16 uint4
      int f = tid + i * 256;
      int r = f >> 4, kg = f & 15;
      *reinterpret_cast<uint4*>(&lXc[r][kg * 8]) =
          *reinterpret_cast<const uint4*>(Xn + (kbase + k0 + r) * DD + kg * 8);
    }
    #pragma unroll
    for (int i = 0; i < 4; ++i) { // lY2: 128 cols x 8 uint4
      int f = tid + i * 256;
      int c = f >> 3, kg = f & 7;
      *reinterpret_cast<uint4*>(&lY2[c][kg * 8]) =
          *reinterpret_cast<const uint4*>(Yt2 + (long)c * NN + kbase + k0 + kg * 8);
    }
    __syncthreads();
    // recompute S tile: rows [sm, sm+16) x cols [sn, sn+32)
    f32x4 sacc[2];
    sacc[0] = {0.f, 0.f, 0.f, 0.f};
    sacc[1] = {0.f, 0.f, 0.f, 0.f};
    #pragma unroll
    for (int ks = 0; ks < 4; ++ks) {
      int kb = ks * 32 + quad * 8;
      bf16x8 a = *reinterpret_cast<const bf16x8*>(&lXr[sm + l16][kb]);
      #pragma unroll
      for (int nt = 0; nt < 2; ++nt) {
        bf16x8 b = *reinterpret_cast<const bf16x8*>(&lXc[sn + nt * 16 + l16][kb]);
        sacc[nt] = __builtin_amdgcn_mfma_f32_16x16x32_bf16(a, b, sacc[nt], 0, 0, 0);
      }
    }
    // mask (same bf16 pattern test as topk) and stage into lAf
    // C/D layout: col = l16 (B-row), row = quad*4 + r (A-row)
    #pragma unroll
    for (int nt = 0; nt < 2; ++nt)
      #pragma unroll
      for (int r = 0; r < 4; ++r) {
        bf16 bv = __float2bfloat16(sacc[nt][r]);
        unsigned short u = reinterpret_cast<unsigned short&>(bv);
        unsigned short t = (unsigned short)(u - p4[r]);
        unsigned short m = (t < b4[r]) ? u : (unsigned short)0;
        reinterpret_cast<unsigned short&>(lAf[sm + quad * 4 + r][sn + nt * 16 + l16]) = m;
      }
    __syncthreads();
    // AV MFMA over this chunk
    #pragma unroll
    for (int ks = 0; ks < 2; ++ks) {
      int kb = ks * 32 + quad * 8;
      bf16x8 afm = *reinterpret_cast<const bf16x8*>(&lAf[sm + l16][kb]);
      #pragma unroll
      for (int ni = 0; ni < 4; ++ni) {
        bf16x8 b2 = *reinterpret_cast<const bf16x8*>(&lY2[wn + ni * 16 + l16][kb]);
        accF[ni] = __builtin_amdgcn_mfma_f32_16x16x32_bf16(afm, b2, accF[ni], 0, 0, 0);
      }
    }
  }
  float* out = Pacc + ((long)blockIdx.y * NN) * DD;
  #pragma unroll
  for (int ni = 0; ni < 4; ++ni)
    #pragma unroll
    for (int r = 0; r < 4; ++r) {
      long row = row0 + sm + quad * 4 + r;
      int col = wn + ni * 16 + l16;
      out[row * DD + col] = accF[ni][r];
    }
}

// ---------------- epilogue: partials + prior (pvec inline) + eye + leaky ----------------
__global__ void epilogue(const float* __restrict__ Pacc, const bf16* __restrict__ Yr1,
                         const bf16* __restrict__ Yr2, const float* __restrict__ impf,
                         const float* __restrict__ Gt, const float* __restrict__ Mt,
                         const float* __restrict__ invRsF,
                         float* __restrict__ Xout, const float* __restrict__ hres,
                         float* __restrict__ outf) {
  int i = blockIdx.x * 256 + threadIdx.x;
  int row = i >> 7, col = i & 127;
  float acc = 0.f;
  #pragma unroll
  for (int s = 0; s < KSLICE; ++s) acc += Pacc[((long)s * NN + row) * DD + col];
  // inline prior_vec: g_t(i)/rowsumP from impf + Gt
  float d = impf[row];
  float a = __expf(d * d * (-1.0f / 32.0f));
  const float ct[5] = {1.0f, 1.0f / 16.0f, 1.0f / 512.0f, 1.0f / 24576.0f, 1.0f / 1572864.0f};
  float g[5];
  float pw = a;
  #pragma unroll
  for (int t = 0; t < 5; ++t) { g[t] = ct[t] * pw; pw *= d; }
  float rs = 1.0f;  // + eye
  #pragma unroll
  for (int t = 0; t < 5; ++t) rs += g[t] * Gt[t];
  float inv = 1.0f / rs;
  float y1 = __bfloat162float(Yr1[i]);
  float y2 = __bfloat162float(Yr2[i]);
  float prior = inv * y1;
  #pragma unroll
  for (int t = 0; t < 5; ++t) prior += (g[t] * inv) * Mt[t * 128 + col];
  float v = prior + invRsF[row] * (acc + y2);
  v = v > 0.f ? v : 0.01f * v;
  if (outf) outf[i] = v + hres[i] * impf[row];
  else      Xout[i] = v;
}

// ---------------- host ----------------

extern "C" void kernel_launch(void* const* d_in, const int* in_sizes, int n_in,
                              void* d_out, int out_size, void* d_ws, size_t ws_size,
                              hipStream_t stream) {
  const void* x_in   = d_in[0];
  const void* imp_in = d_in[1];
  const void* W1 = d_in[2];
  const void* W2 = d_in[3];
  float* out = (float*)d_out;

  char* ws = (char*)d_ws;
  size_t o = 0;
  auto alloc = [&](size_t bytes) { void* p = ws + o; o += (bytes + 511) & ~511ull; return p; };
  bf16*  Af   = (bf16*)alloc((size_t)NN * NN * 2);    // 134 MB raw similarity S (topk input)
  float* Pacc = (float*)alloc((size_t)KSLICE * NN * DD * 4);  // 16 MB split-K partials
  float* xf1  = (float*)alloc((size_t)NN * DD * 4);   // layer-0 output (= h for residual)
  bf16*  xnb  = (bf16*)alloc((size_t)NN * DD * 2);
  bf16*  xb   = (bf16*)alloc((size_t)NN * DD * 2);
  bf16*  Yt1  = (bf16*)alloc((size_t)NN * DD * 2);    // [128][8192] (x@W1)^T
  bf16*  Yt2  = (bf16*)alloc((size_t)NN * DD * 2);
  bf16*  Yr1  = (bf16*)alloc((size_t)NN * DD * 2);    // [8192][128] row-major copies
  bf16*  Yr2  = (bf16*)alloc((size_t)NN * DD * 2);
  bf16*  Wt1  = (bf16*)alloc((size_t)2 * DD * DD * 2);
  bf16*  Wt2  = (bf16*)alloc((size_t)2 * DD * DD * 2);
  float* impf = (float*)alloc((size_t)NN * 4);
  float* Mt   = (float*)alloc((size_t)5 * 128 * 4);
  float* Gt   = (float*)alloc((size_t)8 * 4);
  float* invRsF = (float*)alloc((size_t)NN * 4);
  unsigned short* kthr = (unsigned short*)alloc((size_t)NN * 2);
  int*   dflag  = (int*)alloc(64);
  (void)ws_size; (void)n_in; (void)in_sizes; (void)out_size;

  detect_dtype<<<1, 256, 0, stream>>>((const unsigned short*)x_in, dflag);
  prep<<<5, 256, 0, stream>>>(imp_in, W1, W2, impf, Wt1, Wt2, dflag);

  for (int l = 0; l < 2; ++l) {
    rownorm<<<NN / 4, 256, 0, stream>>>(l ? (const void*)xf1 : x_in, dflag, l ? 0 : 1, xnb, xb);
    gemm_y_dual<<<dim3(4, 64), 256, 0, stream>>>(xb, Wt1 + l * DD * DD, Wt2 + l * DD * DD,
                                                 Yt1, Yt2, Yr1, Yr2);
    prior_reduce<<<129, 256, 0, stream>>>(impf, Yt1, Mt, Gt);
    gemm_s<<<dim3(NN / 64, NN / 128), 256, 0, stream>>>(xnb, Af);
    topk_thresh<<<NN / 4, 256, 0, stream>>>(Af, kthr, invRsF);
    fused_av_recompute<<<dim3(NN / 32, KSLICE), 256, 0, stream>>>(xnb, Yt2, kthr, Pacc);
    if (l == 0)
      epilogue<<<NN * DD / 256, 256, 0, stream>>>(Pacc, Yr1, Yr2, impf, Gt, Mt, invRsF,
                                                  xf1, nullptr, nullptr);
    else
      epilogue<<<NN * DD / 256, 256, 0, stream>>>(Pacc, Yr1, Yr2, impf, Gt, Mt, invRsF,
                                                  nullptr, xf1, out);
  }
}